// Round 2
// baseline (732.553 us; speedup 1.0000x reference)
//
#include <hip/hip_runtime.h>

// CRF Viterbi decode (B=512, T=512, S=64).
// R11: TWO independent batches per (single) wave, instruction-interleaved.
//
// R10 (1 batch/wave, no barriers) measured 1672 cy/step with only ~660 cy of
// VALU issue -> ~1000 cy/step of intra-wave stall (readlane SGPR-write->read
// hazards, cmp->cndmask hazards, dependent-VALU latency), unhideable with one
// wave per SIMD. Two independent Viterbi chains in the SAME wave give the
// scheduler material to fill those bubbles: tr[64] is shared, every other
// register is per-chain, steps are emitted A0,B0,A1,B1,... so adjacent
// instructions are independent. Bounded downside: zero overlap == R10 time.
//
// Layout per chain: lane n owns tag n; full trans row trans[n][0..63] in 64
// shared VGPRs. Per step: 64 literal-lane readlanes + adds, 8 independent
// running argmax chains of 8 (strict >, ascending p => first-argmax), then a
// left-priority merge tree. fmaxf on ties keeps identical values. Exact jnp
// semantics (validated in R9/R10).
//
// Backpointers: 4 steps packed per dword, two 32KB logs = 64KB LDS exactly.
// Backtrace emits ys directly to global (scalar stores from lane 0), both
// chains interleaved. Output: out[0..B) = path_score,
// out[B + b*(T-1) + t] = (float)tag.

constexpr int Bz = 512;
constexpr int Tz = 512;
constexpr int Sz = 64;
constexpr int GRID = Bz / 2;           // 256 blocks, 2 batches per block
constexpr float NEGINF = -10000.0f;

__device__ __forceinline__ float rlf(float x, int lane) {
    return __int_as_float(__builtin_amdgcn_readlane(__float_as_int(x), lane));
}

__global__ __launch_bounds__(64)
void crf_viterbi_kernel(const float* __restrict__ logits,
                        const float* __restrict__ masks,
                        const float* __restrict__ trans,
                        float* __restrict__ out)
{
    const int n  = threadIdx.x;          // lane id == tag id
    const int bA = blockIdx.x;           // chain A batch
    const int bB = blockIdx.x + GRID;    // chain B batch

    // two packed backpointer logs, [chain][group][tag], 4 steps/dword: 64 KB
    __shared__ unsigned bp[2 * 128 * 64];

    // full transitions row for this lane's tag (shared by both chains)
    float tr[64];
    {
        const float4* tr4 = reinterpret_cast<const float4*>(trans + (size_t)n * Sz);
        #pragma unroll
        for (int k = 0; k < 16; ++k) {
            float4 t = tr4[k];
            tr[4 * k + 0] = t.x; tr[4 * k + 1] = t.y;
            tr[4 * k + 2] = t.z; tr[4 * k + 3] = t.w;
        }
    }

    float fvA = (n == 0) ? 0.0f : NEGINF;
    float fvB = (n == 0) ? 0.0f : NEGINF;

    const float* lgbaseA = logits + (size_t)bA * Tz * Sz;
    const float* lgbaseB = logits + (size_t)bB * Tz * Sz;
    const float* mkbaseA = masks + (size_t)bA * Tz;
    const float* mkbaseB = masks + (size_t)bB * Tz;

    // group-of-4 software-pipelined prefetch (2 groups deep), per chain
    float lgcA[4], lgnA[4], mkcA[4], mknA[4];
    float lgcB[4], lgnB[4], mkcB[4], mknB[4];
    #pragma unroll
    for (int k = 0; k < 4; ++k) {
        lgcA[k] = lgbaseA[(1 + k) * Sz + n];  mkcA[k] = mkbaseA[1 + k];
        lgnA[k] = lgbaseA[(5 + k) * Sz + n];  mknA[k] = mkbaseA[5 + k];
        lgcB[k] = lgbaseB[(1 + k) * Sz + n];  mkcB[k] = mkbaseB[1 + k];
        lgnB[k] = lgbaseB[(5 + k) * Sz + n];  mknB[k] = mkbaseB[5 + k];
    }

    unsigned pkA = 0, pkB = 0;

    // ---- one Viterbi step for one chain (compile-time k => literal lanes) ----
    auto step = [&](int k, float lg, float mk, float& fv, unsigned& pk) -> float {
        // 8 independent running chains over prevs (8 each). Ascending p with
        // strict > keeps the EARLIEST p on ties; fmaxf on a tie selects the
        // identical value. Exact jnp first-argmax.
        float m[8]; int id[8];
        #pragma unroll
        for (int c = 0; c < 8; ++c) {
            m[c]  = rlf(fv, 8 * c) + tr[8 * c];
            id[c] = 8 * c;
            #pragma unroll
            for (int j = 1; j < 8; ++j) {
                const int p = 8 * c + j;
                float cand = rlf(fv, p) + tr[p];
                bool g = cand > m[c];          // uses OLD m[c]
                id[c] = g ? p : id[c];
                m[c]  = fmaxf(m[c], cand);
            }
        }
        // merge 8 chain results, left priority on ties (strict >)
        #pragma unroll
        for (int st = 1; st < 8; st <<= 1) {
            #pragma unroll
            for (int c = 0; c < 8; c += 2 * st) {
                bool g = m[c + st] > m[c];
                id[c] = g ? id[c + st] : id[c];
                m[c]  = fmaxf(m[c], m[c + st]);
            }
        }
        pk |= ((unsigned)id[0]) << (8 * k);
        float mm = m[0];
        fv = mm + lg * mk;                     // mask multiplies emission only
        return mm;                             // pre-feat max (for path_score)
    };

    // main: groups g = 0..126 cover steps i = 4g+k (i <= 507)
    for (int g = 0; g < 127; ++g) {
        step(0, lgcA[0], mkcA[0], fvA, pkA);
        step(0, lgcB[0], mkcB[0], fvB, pkB);
        step(1, lgcA[1], mkcA[1], fvA, pkA);
        step(1, lgcB[1], mkcB[1], fvB, pkB);
        step(2, lgcA[2], mkcA[2], fvA, pkA);
        step(2, lgcB[2], mkcB[2], fvB, pkB);
        step(3, lgcA[3], mkcA[3], fvA, pkA);
        step(3, lgcB[3], mkcB[3], fvB, pkB);

        bp[g * 64 + n]        = pkA;           // 64 consecutive dwords each:
        bp[8192 + g * 64 + n] = pkB;           // conflict-free
        pkA = 0; pkB = 0;

        // rotate prefetch; issue loads for group g+2 (rows 4g+9 .. 4g+12)
        #pragma unroll
        for (int k = 0; k < 4; ++k) {
            lgcA[k] = lgnA[k]; mkcA[k] = mknA[k];
            lgcB[k] = lgnB[k]; mkcB[k] = mknB[k];
        }
        #pragma unroll
        for (int k = 0; k < 4; ++k) {
            int t = 4 * g + 9 + k;
            t = (t < Tz) ? t : (Tz - 1);
            lgnA[k] = lgbaseA[t * Sz + n];  mknA[k] = mkbaseA[t];
            lgnB[k] = lgbaseB[t * Sz + n];  mknB[k] = mkbaseB[t];
        }
    }

    // tail: steps 508, 509, 510 (group 127, k = 0..2)
    step(0, lgcA[0], mkcA[0], fvA, pkA);
    step(0, lgcB[0], mkcB[0], fvB, pkB);
    step(1, lgcA[1], mkcA[1], fvA, pkA);
    step(1, lgcB[1], mkcB[1], fvB, pkB);
    float pscA = step(2, lgcA[2], mkcA[2], fvA, pkA);
    float pscB = step(2, lgcB[2], mkcB[2], fvB, pkB);
    bp[127 * 64 + n]        = pkA;             // flush steps 508..510
    bp[8192 + 127 * 64 + n] = pkB;
    if (n == 63) {                             // path_score = vmaxs[-1][:,63]
        out[bA] = pscA;
        out[bB] = pscB;
    }

    // ---- backtrace (intra-wave; same-wave DS ops complete in order) ----
    unsigned wcA = bp[127 * 64 + n];
    unsigned wcB = bp[8192 + 127 * 64 + n];
    int tagA = (__builtin_amdgcn_readlane((int)wcA, 63) >> 16) & 255;  // bptrs[510][63]
    int tagB = (__builtin_amdgcn_readlane((int)wcB, 63) >> 16) & 255;

    float* oA = out + Bz + (size_t)bA * (Tz - 1);
    float* oB = out + Bz + (size_t)bB * (Tz - 1);

    for (int g = 127; g >= 0; --g) {
        unsigned wnA = (g > 0) ? bp[(g - 1) * 64 + n] : 0u;         // prefetch
        unsigned wnB = (g > 0) ? bp[8192 + (g - 1) * 64 + n] : 0u;
        const int smax = (g == 127) ? 2 : 3;
        for (int s = smax; s >= 0; --s) {
            int idx = 4 * g + s;
            if (n == 0) {                       // emit BEFORE following ptr
                oA[idx] = (float)tagA;
                oB[idx] = (float)tagB;
            }
            int wdA = __builtin_amdgcn_readlane((int)wcA, tagA);    // uniform lane idx
            int wdB = __builtin_amdgcn_readlane((int)wcB, tagB);
            tagA = (wdA >> (8 * s)) & 255;
            tagB = (wdB >> (8 * s)) & 255;
        }
        wcA = wnA; wcB = wnB;
    }
}

extern "C" void kernel_launch(void* const* d_in, const int* in_sizes, int n_in,
                              void* d_out, int out_size, void* d_ws, size_t ws_size,
                              hipStream_t stream) {
    const float* logits = (const float*)d_in[0];
    const float* masks  = (const float*)d_in[1];
    const float* trans  = (const float*)d_in[2];
    float* out = (float*)d_out;
    (void)in_sizes; (void)n_in; (void)out_size; (void)d_ws; (void)ws_size;

    crf_viterbi_kernel<<<dim3(GRID), dim3(64), 0, stream>>>(logits, masks, trans, out);
}

// Round 4
// 570.826 us; speedup vs baseline: 1.2833x; 1.2833x over previous
//
#include <hip/hip_runtime.h>

// CRF Viterbi decode (B=512, T=512, S=64).
// R12 (resubmit — round 3 failed on GPU acquisition, kernel never ran):
// LDS-broadcast fv + max3 tree on the critical path + trailing eq-scan
// argmax. One batch per wave, 512 blocks (R10 placement).
//
// Diagnosis history:
//  - R10 (readlane broadcast): 1672 cy/step vs ~654 cy issue. Stall = 64x
//    VALU-writes-SGPR -> VALU-reads-SGPR wait states + cmp->cndmask chains.
//  - R11 (2 chains/wave): ZERO interleave, SGPR_Count pegged at 112 -- the
//    64 readlane results per chain exhaust SGPRs, scheduler serialized.
// Fix: broadcast fv through LDS (VGPR destinations, ~no SGPRs):
//    ds_write_b32 own fv -> 16x uniform-address ds_read_b128 (broadcast,
//    conflict-free). Critical chain per step is now: write -> reads -> 64
//    v_add -> ~32 v_max3 (depth 4) -> feat update. The argmax (backpointer)
//    is OFF the chain: eq-scan vs the max M (v_cmp_eq + v_cndmask, 8
//    independent chains of 8, descending => first index; v_min_u32 merge),
//    scheduled into the next step's LDS shadow.
// Exactness: max tree == jnp.max (no NaNs, order-independent for floats);
// eq-scan smallest p with c[p]==M == jnp first-argmax; feat update uses
// __fmul_rn/__fadd_rn (mul-then-add, no contraction; masks==1 makes this
// moot but pin it anyway). Backtrace + bp packing identical to R10
// (validated). Output: out[0..B) = path_score, out[B + b*(T-1) + t] = tag.

constexpr int Bz = 512;
constexpr int Tz = 512;
constexpr int Sz = 64;
constexpr float NEGINF = -10000.0f;

__device__ __forceinline__ float max3(float a, float b, float c) {
    return fmaxf(fmaxf(a, b), c);   // clang folds to v_max3_f32
}

__global__ __launch_bounds__(64)
void crf_viterbi_kernel(const float* __restrict__ logits,
                        const float* __restrict__ masks,
                        const float* __restrict__ trans,
                        float* __restrict__ out)
{
    const int n = threadIdx.x;       // lane id == tag id
    const int b = blockIdx.x;        // one batch element per (single-wave) block

    __shared__ unsigned bp[128 * 64];            // packed backpointers, 32 KB
    __shared__ __align__(16) float fvb[2][64];   // fv broadcast, double-buffered
    __shared__ float ys[Tz - 1];                 // emitted tags (backtrace)

    // full transitions row for this lane's tag: tr[p] = trans[n][p]
    float tr[64];
    {
        const float4* tr4 = reinterpret_cast<const float4*>(trans + (size_t)n * Sz);
        #pragma unroll
        for (int k = 0; k < 16; ++k) {
            float4 t = tr4[k];
            tr[4 * k + 0] = t.x; tr[4 * k + 1] = t.y;
            tr[4 * k + 2] = t.z; tr[4 * k + 3] = t.w;
        }
    }

    float fv = (n == 0) ? 0.0f : NEGINF;

    const float* lgbase = logits + (size_t)b * Tz * Sz;
    const float* mkbase = masks + (size_t)b * Tz;

    // group-of-4 software-pipelined prefetch (2 groups deep)
    float lgc[4], lgn[4], mkc[4], mkn[4];
    #pragma unroll
    for (int k = 0; k < 4; ++k) {
        lgc[k] = lgbase[(1 + k) * Sz + n];
        mkc[k] = mkbase[1 + k];
        lgn[k] = lgbase[(5 + k) * Sz + n];
        mkn[k] = mkbase[5 + k];
    }

    unsigned pk = 0;

    // ---- one Viterbi step (compile-time k => literal buffer/shift) ----
    auto step = [&](int k, float lg, float mk) -> float {
        const int buf = k & 1;                    // compile-time parity
        fvb[buf][n] = fv;                         // ds_write_b32 (broadcast src)

        // uniform-address broadcast reads: all lanes fetch fv[0..63]
        float c[64];
        {
            const float4* f4 = reinterpret_cast<const float4*>(&fvb[buf][0]);
            #pragma unroll
            for (int i = 0; i < 16; ++i) {
                float4 t = f4[i];
                c[4 * i + 0] = t.x + tr[4 * i + 0];
                c[4 * i + 1] = t.y + tr[4 * i + 1];
                c[4 * i + 2] = t.z + tr[4 * i + 2];
                c[4 * i + 3] = t.w + tr[4 * i + 3];
            }
        }

        // ---- max via 3-ary tree (exact: plain fmax, no NaNs in data) ----
        float t1[21];
        #pragma unroll
        for (int i = 0; i < 21; ++i)
            t1[i] = max3(c[3 * i], c[3 * i + 1], c[3 * i + 2]);   // covers 0..62
        float t2[7];
        #pragma unroll
        for (int i = 0; i < 7; ++i)
            t2[i] = max3(t1[3 * i], t1[3 * i + 1], t1[3 * i + 2]);
        float w0 = max3(t2[0], t2[1], t2[2]);
        float w1 = max3(t2[3], t2[4], t2[5]);
        float w2 = fmaxf(t2[6], c[63]);
        float M  = max3(w0, w1, w2);

        // ---- trailing argmax: eq-scan, 8 chains of 8, descending ----
        // Descending overwrite-on-equal => smallest p per chain; v_min merge
        // => global first argmax. Exact jnp semantics. Off the fv chain.
        int id8[8];
        #pragma unroll
        for (int c8 = 0; c8 < 8; ++c8) {
            int idx = 64;                         // sentinel (never survives)
            #pragma unroll
            for (int j = 7; j >= 0; --j) {
                const int p = 8 * c8 + j;
                idx = (c[p] == M) ? p : idx;
            }
            id8[c8] = idx;
        }
        #pragma unroll
        for (int st = 1; st < 8; st <<= 1)
            #pragma unroll
            for (int c2 = 0; c2 < 8; c2 += 2 * st)
                id8[c2] = min(id8[c2], id8[c2 + st]);

        pk |= ((unsigned)id8[0]) << (8 * k);
        fv = __fadd_rn(M, __fmul_rn(lg, mk));     // mask multiplies emission only
        return M;                                 // pre-feat max (for path_score)
    };

    // main: groups g = 0..126 cover steps i = 4g+k (i <= 507)
    for (int g = 0; g < 127; ++g) {
        step(0, lgc[0], mkc[0]);
        step(1, lgc[1], mkc[1]);
        step(2, lgc[2], mkc[2]);
        step(3, lgc[3], mkc[3]);

        bp[g * 64 + n] = pk;                   // 64 consecutive dwords: conflict-free
        pk = 0;

        // rotate prefetch; issue loads for group g+2 (rows 4g+9 .. 4g+12)
        #pragma unroll
        for (int k = 0; k < 4; ++k) { lgc[k] = lgn[k]; mkc[k] = mkn[k]; }
        #pragma unroll
        for (int k = 0; k < 4; ++k) {
            int t = 4 * g + 9 + k;
            t = (t < Tz) ? t : (Tz - 1);
            lgn[k] = lgbase[t * Sz + n];
            mkn[k] = mkbase[t];
        }
    }

    // tail: steps 508, 509, 510 (group 127, k = 0..2)
    step(0, lgc[0], mkc[0]);
    step(1, lgc[1], mkc[1]);
    float psc = step(2, lgc[2], mkc[2]);
    bp[127 * 64 + n] = pk;                     // flush steps 508..510
    if (n == 63) out[b] = psc;                 // path_score = vmaxs[-1][:,63]

    // ---- backtrace (intra-wave; validated R10 readlane chain) ----
    unsigned wcur = bp[127 * 64 + n];
    int w127_63 = __builtin_amdgcn_readlane((int)wcur, 63);
    int tag = (w127_63 >> 16) & 255;           // t0 = bptrs[510][63]

    for (int g = 127; g >= 0; --g) {
        unsigned wnext = (g > 0) ? bp[(g - 1) * 64 + n] : 0u;  // prefetch
        const int smax = (g == 127) ? 2 : 3;
        for (int s = smax; s >= 0; --s) {
            int idx = 4 * g + s;
            if (n == 0) ys[idx] = (float)tag;  // emit BEFORE following ptr
            int wd = __builtin_amdgcn_readlane((int)wcur, tag);  // tag is uniform
            tag = (wd >> (8 * s)) & 255;
        }
        wcur = wnext;
    }

    __syncthreads();                           // single wave: orders ys for copy
    float* outseq = out + Bz + (size_t)b * (Tz - 1);
    for (int k = n; k < Tz - 1; k += 64) outseq[k] = ys[k];
}

extern "C" void kernel_launch(void* const* d_in, const int* in_sizes, int n_in,
                              void* d_out, int out_size, void* d_ws, size_t ws_size,
                              hipStream_t stream) {
    const float* logits = (const float*)d_in[0];
    const float* masks  = (const float*)d_in[1];
    const float* trans  = (const float*)d_in[2];
    float* out = (float*)d_out;
    (void)in_sizes; (void)n_in; (void)out_size; (void)d_ws; (void)ws_size;

    crf_viterbi_kernel<<<dim3(Bz), dim3(64), 0, stream>>>(logits, masks, trans, out);
}